// Round 1
// baseline (685.719 us; speedup 1.0000x reference)
//
#include <hip/hip_runtime.h>
#include <stdint.h>

// LoRA: y = dropout( (x @ (2 * B@A)^T) ), p=0.1, mask = jax.random.bernoulli(key(42), 0.9)
// x: [4,4096,4096] f32  -> flatten to M=16384 rows, K=4096
// lora_A: [16,4096] f32 ; lora_B: [4096,16] f32 ; out: [16384,4096] f32
//
// Dropout mask reproduction (threefry2x32, JAX partitionable layout — default
// since JAX 0.4.36): for flat element i, counter=(hi=0, lo=i), key=(0,42),
// bits = out0 ^ out1; u = bitcast((bits>>9)|0x3f800000) - 1.0f; keep iff u < 0.9f.
// FALLBACK if this fails ~1.7 absmax: original layout pairs (j, j+N/2).

#define M_TOTAL 16384
#define IN_F 4096
#define OUT_F 4096

__device__ __forceinline__ uint32_t tf_bits(uint32_t idx) {
  const uint32_t ks0 = 0u;
  const uint32_t ks1 = 42u;
  const uint32_t ks2 = 0u ^ 42u ^ 0x1BD11BDAu;
  uint32_t x0 = 0u + ks0;      // counts_hi = 0 (N < 2^32)
  uint32_t x1 = idx + ks1;     // counts_lo = flat index
#define TFR(r) { x0 += x1; x1 = (x1 << (r)) | (x1 >> (32 - (r))); x1 ^= x0; }
  TFR(13) TFR(15) TFR(26) TFR(6)   x0 += ks1; x1 += ks2 + 1u;
  TFR(17) TFR(29) TFR(16) TFR(24)  x0 += ks2; x1 += ks0 + 2u;
  TFR(13) TFR(15) TFR(26) TFR(6)   x0 += ks0; x1 += ks1 + 3u;
  TFR(17) TFR(29) TFR(16) TFR(24)  x0 += ks1; x1 += ks2 + 4u;
  TFR(13) TFR(15) TFR(26) TFR(6)   x0 += ks2; x1 += ks0 + 5u;
#undef TFR
  return x0 ^ x1;   // partitionable 32-bit draw: out0 ^ out1
}

__device__ __forceinline__ float apply_dropout(float v, uint32_t idx) {
  uint32_t bits = tf_bits(idx);
  float u = __uint_as_float((bits >> 9) | 0x3f800000u) - 1.0f;
  // keep iff u < 0.9f (f32 compare, identical to JAX); kept values / 0.9
  return (u < 0.9f) ? v * (1.0f / 0.9f) : 0.0f;
}

// ---------------- Pass 1: t[m, r] = 2 * sum_i x[m,i] * A[r,i] ----------------
// 16 rows per block (amortize A through L1/L2). tid: row = tid>>4, chunk = tid&15.
// Lanes 16k..16k+15 cover one row; x loads are 16 consecutive float4 per group.
__global__ __launch_bounds__(256) void lora_xa_kernel(
    const float* __restrict__ x, const float* __restrict__ A,
    float* __restrict__ t) {
  const int tid = threadIdx.x;
  const int row_in_blk = tid >> 4;   // 0..15
  const int chunk = tid & 15;        // 0..15
  const int m = blockIdx.x * 16 + row_in_blk;

  const float4* x4 = (const float4*)(x + (size_t)m * IN_F);
  const float4* A4 = (const float4*)A;   // [16][1024] float4

  float acc[16];
#pragma unroll
  for (int r = 0; r < 16; ++r) acc[r] = 0.0f;

  for (int j = 0; j < 64; ++j) {
    const int f4 = chunk + j * 16;
    const float4 xv = x4[f4];
#pragma unroll
    for (int r = 0; r < 16; ++r) {
      const float4 av = A4[r * 1024 + f4];
      acc[r] += xv.x * av.x + xv.y * av.y + xv.z * av.z + xv.w * av.w;
    }
  }

  // Reduce across the 16 lanes of each contiguous 16-lane group (xor stays in group).
#pragma unroll
  for (int off = 1; off < 16; off <<= 1) {
#pragma unroll
    for (int r = 0; r < 16; ++r) acc[r] += __shfl_xor(acc[r], off, 64);
  }

  // All 16 lanes now hold the full acc[0..15]; lane `chunk` writes element `chunk`.
  float out = acc[0];
#pragma unroll
  for (int r = 1; r < 16; ++r) out = (chunk == r) ? acc[r] : out;
  t[(size_t)m * 16 + chunk] = out * 2.0f;   // fold SCALING = 32/16 = 2
}

// ---------------- Pass 2: y[m,o] = dropout( sum_r t[m,r] * B[o,r] ) ----------
// Block: 64 rows x 1024 cols. Thread owns 4 consecutive cols (B frag in regs),
// loops 64 rows with t staged in LDS (broadcast reads).
__global__ __launch_bounds__(256) void lora_tb_kernel(
    const float* __restrict__ t, const float* __restrict__ B,
    float* __restrict__ y) {
  __shared__ float ts[64 * 16];   // 4 KB
  const int tid = threadIdx.x;
  const int colblk = blockIdx.x & 3;        // 4 col-blocks of 1024
  const int rowblk = blockIdx.x >> 2;       // 256 row-blocks of 64
  const int m0 = rowblk * 64;
  const int o = colblk * 1024 + tid * 4;    // this thread's first column

  // Stage t rows for this block: 1024 floats = 256 float4.
  ((float4*)ts)[tid] = ((const float4*)(t + (size_t)m0 * 16))[tid];

  // Load B[o..o+3][0..15] into registers: 16 float4 (64 VGPRs).
  float4 b[4][4];
#pragma unroll
  for (int c = 0; c < 4; ++c) {
#pragma unroll
    for (int q = 0; q < 4; ++q)
      b[c][q] = ((const float4*)(B + (size_t)(o + c) * 16))[q];
  }
  __syncthreads();

  for (int mi = 0; mi < 64; ++mi) {
    const int m = m0 + mi;
    float tr[16];
#pragma unroll
    for (int r = 0; r < 16; ++r) tr[r] = ts[mi * 16 + r];  // LDS broadcast

    float accv[4];
#pragma unroll
    for (int c = 0; c < 4; ++c) {
      float s = 0.0f;
#pragma unroll
      for (int q = 0; q < 4; ++q) {
        const float4 bb = b[c][q];
        s += tr[4 * q + 0] * bb.x + tr[4 * q + 1] * bb.y +
             tr[4 * q + 2] * bb.z + tr[4 * q + 3] * bb.w;
      }
      accv[c] = s;
    }

    const uint32_t base = (uint32_t)m * (uint32_t)OUT_F + (uint32_t)o;
    float4 res;
    res.x = apply_dropout(accv[0], base + 0u);
    res.y = apply_dropout(accv[1], base + 1u);
    res.z = apply_dropout(accv[2], base + 2u);
    res.w = apply_dropout(accv[3], base + 3u);
    ((float4*)y)[((size_t)m * OUT_F + o) >> 2] = res;
  }
}

extern "C" void kernel_launch(void* const* d_in, const int* in_sizes, int n_in,
                              void* d_out, int out_size, void* d_ws, size_t ws_size,
                              hipStream_t stream) {
  const float* x = (const float*)d_in[0];   // [16384, 4096]
  const float* A = (const float*)d_in[1];   // [16, 4096]
  const float* B = (const float*)d_in[2];   // [4096, 16]
  float* y = (float*)d_out;                 // [16384, 4096]
  float* t = (float*)d_ws;                  // [16384, 16] scratch (1 MB)

  lora_xa_kernel<<<M_TOTAL / 16, 256, 0, stream>>>(x, A, t);
  lora_tb_kernel<<<(M_TOTAL / 64) * (OUT_F / 1024), 256, 0, stream>>>(t, B, y);
}